// Round 14
// baseline (113.189 us; speedup 1.0000x reference)
//
#include <hip/hip_runtime.h>
#include <hip/hip_bf16.h>

typedef short bf16x8 __attribute__((ext_vector_type(8)));
typedef float f32x4 __attribute__((ext_vector_type(4)));

#define T_LEN 512
#define BATCH 32
#define D 512
#define M_TOT (T_LEN * BATCH) /* 16384 */
#define NLAYER 4

/* ---- layer-0 GEMM (fp32 A and B, reg-staged converts) ---- */
#define BM 128
#define BN 128
#define BK 64
#define NT (D / BK) /* 8 K-tiles */
#define EP 72

/* ---- resident-B GEMM (layers 1-3): XOR-swizzled B, ring-3 A ---- */
#define QBN 64                /* output cols per block */
#define QWROWS 32             /* private M-rows per wave */
#define QBM 256               /* 8 waves x 32 rows */
#define QB_ELEMS (QBN * D)    /* 32768 elems = 64KB resident B */
#define QA_SLOT (QWROWS * BK) /* 2048 elems = 4KB per A slot */
#define QSMEM_BYTES ((QB_ELEMS + 8 * 3 * QA_SLOT) * 2) /* 163840 B = 160KB exact */
#define QEP 72

#define CH 32            /* scan chunk length */
#define NCH (T_LEN / CH) /* 16 chunks */

#define SBAR()                             \
    do {                                   \
        __builtin_amdgcn_s_barrier();      \
        __builtin_amdgcn_sched_barrier(0); \
    } while (0)
#define VMCNT(n)                                              \
    do {                                                      \
        asm volatile("s_waitcnt vmcnt(" #n ")" ::: "memory"); \
        __builtin_amdgcn_sched_barrier(0);                    \
    } while (0)
#define LGKM0()                                               \
    do {                                                      \
        asm volatile("s_waitcnt lgkmcnt(0)" ::: "memory");    \
        __builtin_amdgcn_sched_barrier(0);                    \
    } while (0)

// ---------------- layer-0 GEMM: A = x fp32, B = W[0] fp32, both reg-staged --
// Proven round-12 structure, unchanged.
__global__ __launch_bounds__(256) void gemm_l0(const float* __restrict__ Agf0,
                                               const float* __restrict__ Bgf0,
                                               const float* __restrict__ bias,
                                               __hip_bfloat16* __restrict__ Cb) {
    constexpr int K = D;
    constexpr int N = D;
    __shared__ __hip_bfloat16 smem[4 * BM * BK]; // 64KB
    __hip_bfloat16* const AsP[2] = {smem, smem + BM * BK};
    __hip_bfloat16* const BsP[2] = {smem + 2 * BM * BK, smem + 3 * BM * BK};

    const int tid  = threadIdx.x;
    const int wave = tid >> 6;
    const int lane = tid & 63;

    const int bid = blockIdx.x;
    const int xcd = bid & 7;
    const int jb  = bid >> 3;
    const int bm  = xcd * 16 + (jb >> 2);
    const int bn  = jb & 3;

    const int wm = (wave >> 1) * 64;
    const int wn = (wave & 1) * 64;

    const int srow = lane >> 3;
    const int scol = ((lane & 7) ^ srow) * 8;

    const float* Agf = Agf0 + (size_t)(bm * BM) * K;
    const float* Bgf = Bgf0 + (size_t)(bn * BN) * K;

    f32x4 acc[4][4] = {};
    float4 va[4][2], vb[4][2];

#define LOAD_F32(vr, base, k0)                                                                       \
    do {                                                                                             \
        _Pragma("unroll") for (int jj = 0; jj < 4; ++jj) {                                           \
            const int rbase = (jj * 4 + wave) * 8;                                                   \
            const float* sp = (base) + (size_t)(rbase + srow) * K + (k0) + scol;                     \
            vr[jj][0] = *(const float4*)sp;                                                          \
            vr[jj][1] = *(const float4*)(sp + 4);                                                    \
        }                                                                                            \
    } while (0)

#define WRITE_BF16(vr, dst)                                                                          \
    do {                                                                                             \
        _Pragma("unroll") for (int jj = 0; jj < 4; ++jj) {                                           \
            const int rbase = (jj * 4 + wave) * 8;                                                   \
            bf16x8 pk;                                                                               \
            _Pragma("unroll") for (int q = 0; q < 4; ++q) {                                          \
                __hip_bfloat16 t0 = __float2bfloat16(((const float*)&vr[jj][0])[q]);                 \
                __hip_bfloat16 t1 = __float2bfloat16(((const float*)&vr[jj][1])[q]);                 \
                pk[q]     = *(const short*)&t0;                                                      \
                pk[q + 4] = *(const short*)&t1;                                                      \
            }                                                                                        \
            *(bf16x8*)(&(dst)[(rbase + srow) * BK + (lane & 7) * 8]) = pk;                           \
        }                                                                                            \
    } while (0)

#define COMPUTE0(buf)                                                                                \
    do {                                                                                             \
        bf16x8 af[4][2], bv[4][2];                                                                   \
        const int fr = lane & 15;                                                                    \
        const int kq = lane >> 4;                                                                    \
        _Pragma("unroll") for (int mi = 0; mi < 4; ++mi) {                                           \
            const int r = wm + mi * 16 + fr;                                                         \
            _Pragma("unroll") for (int kh = 0; kh < 2; ++kh) {                                       \
                const int c = ((kh * 4 + kq) ^ (fr & 7)) * 8;                                        \
                af[mi][kh] = *(const bf16x8*)(&AsP[buf][r * BK + c]);                                \
            }                                                                                        \
        }                                                                                            \
        _Pragma("unroll") for (int ni = 0; ni < 4; ++ni) {                                           \
            const int r = wn + ni * 16 + fr;                                                         \
            _Pragma("unroll") for (int kh = 0; kh < 2; ++kh) {                                       \
                const int c = ((kh * 4 + kq) ^ (fr & 7)) * 8;                                        \
                bv[ni][kh] = *(const bf16x8*)(&BsP[buf][r * BK + c]);                                \
            }                                                                                        \
        }                                                                                            \
        _Pragma("unroll") for (int kh = 0; kh < 2; ++kh)                                             \
            _Pragma("unroll") for (int mi = 0; mi < 4; ++mi)                                         \
                _Pragma("unroll") for (int ni = 0; ni < 4; ++ni)                                     \
                    acc[mi][ni] = __builtin_amdgcn_mfma_f32_16x16x32_bf16(af[mi][kh], bv[ni][kh],    \
                                                                          acc[mi][ni], 0, 0, 0);    \
    } while (0)

    LOAD_F32(va, Agf, 0);
    LOAD_F32(vb, Bgf, 0);
    WRITE_BF16(va, AsP[0]);
    WRITE_BF16(vb, BsP[0]);
    __syncthreads();
    int cur = 0;
#pragma unroll
    for (int kt = 1; kt < NT; ++kt) {
        LOAD_F32(va, Agf, kt * BK);
        LOAD_F32(vb, Bgf, kt * BK);
        COMPUTE0(cur);
        WRITE_BF16(va, AsP[cur ^ 1]);
        WRITE_BF16(vb, BsP[cur ^ 1]);
        __syncthreads();
        cur ^= 1;
    }
    COMPUTE0(cur);
    __syncthreads();

    {
        __hip_bfloat16* S = smem + wave * (64 * EP);
        const int cfr = lane & 15;
        const int cfq = lane >> 4;
        float bs[4];
#pragma unroll
        for (int ni = 0; ni < 4; ++ni) bs[ni] = bias[bn * BN + wn + ni * 16 + cfr];
#pragma unroll
        for (int mi = 0; mi < 4; ++mi)
#pragma unroll
            for (int ni = 0; ni < 4; ++ni)
#pragma unroll
                for (int r = 0; r < 4; ++r)
                    S[(mi * 16 + cfq * 4 + r) * EP + ni * 16 + cfr] =
                        __float2bfloat16(acc[mi][ni][r] + bs[ni]);
        const int rq = lane >> 3;
        const int cl = (lane & 7) * 8;
#pragma unroll
        for (int p = 0; p < 8; ++p) {
            const int lr = p * 8 + rq;
            bf16x8 v = *(const bf16x8*)(S + lr * EP + cl);
            *(bf16x8*)(&Cb[(size_t)(bm * BM + wm + lr) * N + bn * BN + wn + cl]) = v;
        }
    }
#undef LOAD_F32
#undef WRITE_BF16
#undef COMPUTE0
}

// ---------------- resident-B GEMM (layers 1-3) ------------------------------
// Round-13 skeleton + ring-3 A pipeline (prefetch distance 3 ~= 810cy in
// flight, covers L3-hit latency of cross-XCD Ab reads). B: [64][512] bf16,
// chunk-XOR swizzle applied on reg-staged ds_write dest; read side identical
// to round 9. LDS = 64KB B + 8 waves x 3 x 4KB A = 160KB exact.
__global__ __launch_bounds__(512) void gemm_resB(const __hip_bfloat16* __restrict__ A,
                                                 const float* __restrict__ Btf,
                                                 const float* __restrict__ bias,
                                                 __hip_bfloat16* __restrict__ Cb) {
    constexpr int K = D;
    constexpr int N = D;
    extern __shared__ __hip_bfloat16 smem[]; // [64KB B][8 waves x 3 x 4KB A]

    const int tid  = threadIdx.x;
    const int wave = tid >> 6;
    const int lane = tid & 63;

    const int bid = blockIdx.x;
    const int xcd = bid & 7;
    const int jb  = bid >> 3;            // 0..63
    const int bm  = xcd * 8 + (jb >> 3); // 0..63
    const int bn  = jb & 7;              // 0..7

    __hip_bfloat16* const Bsm = smem;
    __hip_bfloat16* const Awv = smem + QB_ELEMS + wave * (3 * QA_SLOT);

    const int srow = lane >> 3;
    const int sch  = lane & 7;

    const __hip_bfloat16* Agw = A + (size_t)(bm * QBM + wave * QWROWS) * K;
    const float* Bgf = Btf + (size_t)(bn * QBN) * K;

    const int fr = lane & 15;
    const int kq = lane >> 4;

    f32x4 acc[2][4] = {};

#define STAGE_A(slot, k0)                                                                            \
    do {                                                                                             \
        _Pragma("unroll") for (int jj = 0; jj < 4; ++jj) {                                           \
            const int rbase = jj * 8;                                                                \
            __builtin_amdgcn_global_load_lds(                                                        \
                (const __attribute__((address_space(1))) void*)(Agw + (size_t)(rbase + srow) * K + (k0) + (sch ^ srow) * 8), \
                (__attribute__((address_space(3))) void*)(Awv + (slot) * QA_SLOT + rbase * BK), 16, 0, 0); \
        }                                                                                            \
    } while (0)

    // ---- prologue: B fp32 regs -> A tiles 0,1,2 (gload_lds) -> B ds_write --
    // B global loads are OLDEST in vmcnt; the compiler's wait before the B
    // ds_writes retires them while the 12 A gload_lds stay in flight.
    {
        float4 vb[8][2];
#pragma unroll
        for (int jj = 0; jj < 8; ++jj) {
            const float* src = Bgf + (size_t)(wave * 8 + jj) * K + lane * 8;
            vb[jj][0] = *(const float4*)src;
            vb[jj][1] = *(const float4*)(src + 4);
        }
        STAGE_A(0, 0);
        STAGE_A(1, BK);
        STAGE_A(2, 2 * BK);
#pragma unroll
        for (int jj = 0; jj < 8; ++jj) {
            const int row = wave * 8 + jj;
            bf16x8 pk;
#pragma unroll
            for (int q = 0; q < 4; ++q) {
                __hip_bfloat16 t0 = __float2bfloat16(((const float*)&vb[jj][0])[q]);
                __hip_bfloat16 t1 = __float2bfloat16(((const float*)&vb[jj][1])[q]);
                pk[q]     = *(const short*)&t0;
                pk[q + 4] = *(const short*)&t1;
            }
            // chunk-XOR swizzle on the write dest (global col = lane*8)
            const int dc = ((lane & ~7) | ((lane & 7) ^ (row & 7))) * 8;
            *(bf16x8*)(&Bsm[row * D + dc]) = pk;
        }
    }
    LGKM0(); // B writes landed (A gload_lds unaffected by lgkm)
    SBAR();  // B published block-wide -- the only barrier

#pragma unroll
    for (int t = 0; t < NT; ++t) {
        // retire exactly the tile we are about to read; keep the rest in flight
        if (t < NT - 2) {
            VMCNT(8);
        } else if (t == NT - 2) {
            VMCNT(4);
        } else {
            VMCNT(0);
        }
        const __hip_bfloat16* Asl = Awv + (t % 3) * QA_SLOT;
        bf16x8 af[2][2], bv[4][2];
#pragma unroll
        for (int mi = 0; mi < 2; ++mi)
#pragma unroll
            for (int kh = 0; kh < 2; ++kh) {
                const int c = ((kh * 4 + kq) ^ (fr & 7)) * 8;
                af[mi][kh] = *(const bf16x8*)(&Asl[(mi * 16 + fr) * BK + c]);
            }
#pragma unroll
        for (int ni = 0; ni < 4; ++ni)
#pragma unroll
            for (int kh = 0; kh < 2; ++kh) {
                const int n = ni * 16 + fr;
                const int c = t * BK + (((kh * 4 + kq) ^ (fr & 7)) * 8);
                bv[ni][kh] = *(const bf16x8*)(&Bsm[n * D + c]);
            }
        LGKM0(); // fragment reads landed in VGPRs: slot t%3 free
        if (t + 3 < NT) STAGE_A(t % 3, (t + 3) * BK); // wave-private, no barrier
        __builtin_amdgcn_sched_barrier(0);
        __builtin_amdgcn_s_setprio(1);
#pragma unroll
        for (int kh = 0; kh < 2; ++kh)
#pragma unroll
            for (int mi = 0; mi < 2; ++mi)
#pragma unroll
                for (int ni = 0; ni < 4; ++ni)
                    acc[mi][ni] = __builtin_amdgcn_mfma_f32_16x16x32_bf16(af[mi][kh], bv[ni][kh],
                                                                          acc[mi][ni], 0, 0, 0);
        __builtin_amdgcn_s_setprio(0);
    }
#undef STAGE_A

    // ---- epilogue: wave-private LDS staging, coalesced stores --------------
    {
        __hip_bfloat16* S = Awv;
        const int cfq = lane >> 4;
        float bs[4];
#pragma unroll
        for (int ni = 0; ni < 4; ++ni) bs[ni] = bias[bn * QBN + ni * 16 + fr];
#pragma unroll
        for (int mi = 0; mi < 2; ++mi)
#pragma unroll
            for (int ni = 0; ni < 4; ++ni)
#pragma unroll
                for (int r = 0; r < 4; ++r)
                    S[(mi * 16 + cfq * 4 + r) * QEP + ni * 16 + fr] =
                        __float2bfloat16(acc[mi][ni][r] + bs[ni]);
        const int rq = lane >> 3;
        const int cl = (lane & 7) * 8;
#pragma unroll
        for (int p = 0; p < 4; ++p) {
            const int lr = p * 8 + rq;
            bf16x8 v = *(const bf16x8*)(S + lr * QEP + cl);
            *(bf16x8*)(&Cb[(size_t)(bm * QBM + wave * QWROWS + lr) * N + bn * QBN + cl]) = v;
        }
    }
}

// ---------------- fused parallel scan: h_t = max(0, a_t + u*h_{t-1}) ---------
// Chunk decomposition (h>=0 domain): F_c(h) = max(m, d + e*h), e = u^CH.
template <int MODE>
__global__ __launch_bounds__(512) void scan_k(const __hip_bfloat16* __restrict__ xh,
                                              const float* __restrict__ u,
                                              float* __restrict__ outf,
                                              __hip_bfloat16* __restrict__ outb) {
    __shared__ float4 md[NCH][32];
    const int i2  = threadIdx.x & 31;
    const int c   = threadIdx.x >> 5; // 0..15
    const int idx = blockIdx.x * 64 + i2 * 2;
    const float u0 = u[idx & (D - 1)];
    const float u1 = u[(idx + 1) & (D - 1)];

    const __hip_bfloat16* p = xh + (size_t)c * CH * M_TOT + idx;
    unsigned int xv[CH];
#pragma unroll
    for (int t = 0; t < CH; ++t) xv[t] = *(const unsigned int*)(p + (size_t)t * M_TOT);

    float m0 = 0.f, d0 = 0.f, m1 = 0.f, d1 = 0.f;
#pragma unroll
    for (int t = 0; t < CH; ++t) {
        const float a0 = __uint_as_float(xv[t] << 16);
        const float a1 = __uint_as_float(xv[t] & 0xffff0000u);
        m0 = fmaxf(fmaf(u0, m0, a0), 0.f);
        d0 = fmaf(u0, d0, a0);
        m1 = fmaxf(fmaf(u1, m1, a1), 0.f);
        d1 = fmaf(u1, d1, a1);
    }
    md[c][i2] = make_float4(m0, d0, m1, d1);
    __syncthreads();

    float e0 = u0 * u0, e1 = u1 * u1;       // u^2
    e0 *= e0; e0 *= e0; e0 *= e0; e0 *= e0; // u^32 == u^CH
    e1 *= e1; e1 *= e1; e1 *= e1; e1 *= e1;
    float h0 = 0.f, h1 = 0.f;
    for (int jj = 0; jj < c; ++jj) {
        const float4 v = md[jj][i2];
        h0 = fmaxf(v.x, fmaf(e0, h0, v.y));
        h1 = fmaxf(v.z, fmaf(e1, h1, v.w));
    }

    const size_t base = (size_t)c * CH * M_TOT + idx;
#pragma unroll
    for (int t = 0; t < CH; ++t) {
        const size_t off = base + (size_t)t * M_TOT;
        const float a0 = __uint_as_float(xv[t] << 16);
        const float a1 = __uint_as_float(xv[t] & 0xffff0000u);
        h0 = fmaxf(fmaf(u0, h0, a0), 0.f);
        h1 = fmaxf(fmaf(u1, h1, a1), 0.f);
        if (MODE & 1) *(float2*)(outf + off) = make_float2(h0, h1);
        if (MODE & 2) {
            __hip_bfloat16 b0 = __float2bfloat16(h0);
            __hip_bfloat16 b1 = __float2bfloat16(h1);
            unsigned int pk = (unsigned int)(*(unsigned short*)&b0) |
                              ((unsigned int)(*(unsigned short*)&b1) << 16);
            *(unsigned int*)(outb + off) = pk;
        }
    }
}

extern "C" void kernel_launch(void* const* d_in, const int* in_sizes, int n_in,
                              void* d_out, int out_size, void* d_ws, size_t ws_size,
                              hipStream_t stream) {
    const float* x = (const float*)d_in[0]; // [T, B, Din]
    const float* W = (const float*)d_in[1]; // [L, Dh, Din]
    const float* b = (const float*)d_in[2]; // [L, Dh]
    const float* u = (const float*)d_in[3]; // [L, Dh]
    float* out = (float*)d_out;             // [T, B, Dh]

    __hip_bfloat16* Ab = (__hip_bfloat16*)d_ws;  // 16.8 MB
    __hip_bfloat16* Xh = Ab + (size_t)M_TOT * D; // 16.8 MB

    (void)hipFuncSetAttribute((const void*)gemm_resB,
                              hipFuncAttributeMaxDynamicSharedMemorySize, QSMEM_BYTES);

    for (int l = 0; l < NLAYER; ++l) {
        if (l == 0) {
            gemm_l0<<<(M_TOT / BM) * (D / BN), 256, 0, stream>>>(x, W, b, Xh);
        } else {
            gemm_resB<<<(M_TOT / QBM) * (D / QBN), 512, QSMEM_BYTES, stream>>>(
                Ab, W + (size_t)l * D * D, b + (size_t)l * D, Xh);
        }
        if (l < NLAYER - 1) {
            scan_k<2><<<M_TOT / 64, 512, 0, stream>>>(Xh, u + (size_t)l * D, nullptr, Ab);
        } else {
            scan_k<1><<<M_TOT / 64, 512, 0, stream>>>(Xh, u + (size_t)l * D, out, nullptr);
        }
    }
}

// Round 15
// 111.172 us; speedup vs baseline: 1.0181x; 1.0181x over previous
//
#include <hip/hip_runtime.h>
#include <hip/hip_bf16.h>

typedef short bf16x8 __attribute__((ext_vector_type(8)));
typedef float f32x4 __attribute__((ext_vector_type(4)));

#define T_LEN 512
#define BATCH 32
#define D 512
#define M_TOT (T_LEN * BATCH) /* 16384 */
#define NLAYER 4

/* ---- layer-0 GEMM (fp32 A and B, reg-staged converts) ---- */
#define BM 128
#define BN 128
#define BK 64
#define NT (D / BK) /* 8 K-tiles */
#define EP 72

/* ---- resident-B GEMM (layers 1-3): fp32 B panel, padded LDS ---- */
#define QBN 64                /* output cols per block */
#define QWROWS 32             /* private M-rows per wave */
#define QBM 256               /* 8 waves x 32 rows */
#define BPAD 520              /* padded B row stride (1040B -> 4-word bank rotation) */
#define QB_ELEMS (QBN * BPAD) /* 33280 elems */
#define QA_SLOT (QWROWS * BK) /* 2048 elems = 4KB per A slot */
#define QSMEM_BYTES ((QB_ELEMS + 8 * 2 * QA_SLOT) * 2) /* 132096 B */
#define QEP 72

#define CH 32            /* scan chunk length */
#define NCH (T_LEN / CH) /* 16 chunks */

#define SBAR()                             \
    do {                                   \
        __builtin_amdgcn_s_barrier();      \
        __builtin_amdgcn_sched_barrier(0); \
    } while (0)
#define VMCNT(n)                                              \
    do {                                                      \
        asm volatile("s_waitcnt vmcnt(" #n ")" ::: "memory"); \
        __builtin_amdgcn_sched_barrier(0);                    \
    } while (0)
#define LGKM(n)                                                \
    do {                                                       \
        asm volatile("s_waitcnt lgkmcnt(" #n ")" ::: "memory");\
        __builtin_amdgcn_sched_barrier(0);                     \
    } while (0)

// ---------------- layer-0 GEMM: A = x fp32, B = W[0] fp32, both reg-staged --
// Proven round-12/13 structure, unchanged.
__global__ __launch_bounds__(256) void gemm_l0(const float* __restrict__ Agf0,
                                               const float* __restrict__ Bgf0,
                                               const float* __restrict__ bias,
                                               __hip_bfloat16* __restrict__ Cb) {
    constexpr int K = D;
    constexpr int N = D;
    __shared__ __hip_bfloat16 smem[4 * BM * BK]; // 64KB
    __hip_bfloat16* const AsP[2] = {smem, smem + BM * BK};
    __hip_bfloat16* const BsP[2] = {smem + 2 * BM * BK, smem + 3 * BM * BK};

    const int tid  = threadIdx.x;
    const int wave = tid >> 6;
    const int lane = tid & 63;

    const int bid = blockIdx.x;
    const int xcd = bid & 7;
    const int jb  = bid >> 3;
    const int bm  = xcd * 16 + (jb >> 2);
    const int bn  = jb & 3;

    const int wm = (wave >> 1) * 64;
    const int wn = (wave & 1) * 64;

    const int srow = lane >> 3;
    const int scol = ((lane & 7) ^ srow) * 8;

    const float* Agf = Agf0 + (size_t)(bm * BM) * K;
    const float* Bgf = Bgf0 + (size_t)(bn * BN) * K;

    f32x4 acc[4][4] = {};
    float4 va[4][2], vb[4][2];

#define LOAD_F32(vr, base, k0)                                                                       \
    do {                                                                                             \
        _Pragma("unroll") for (int jj = 0; jj < 4; ++jj) {                                           \
            const int rbase = (jj * 4 + wave) * 8;                                                   \
            const float* sp = (base) + (size_t)(rbase + srow) * K + (k0) + scol;                     \
            vr[jj][0] = *(const float4*)sp;                                                          \
            vr[jj][1] = *(const float4*)(sp + 4);                                                    \
        }                                                                                            \
    } while (0)

#define WRITE_BF16(vr, dst)                                                                          \
    do {                                                                                             \
        _Pragma("unroll") for (int jj = 0; jj < 4; ++jj) {                                           \
            const int rbase = (jj * 4 + wave) * 8;                                                   \
            bf16x8 pk;                                                                               \
            _Pragma("unroll") for (int q = 0; q < 4; ++q) {                                          \
                __hip_bfloat16 t0 = __float2bfloat16(((const float*)&vr[jj][0])[q]);                 \
                __hip_bfloat16 t1 = __float2bfloat16(((const float*)&vr[jj][1])[q]);                 \
                pk[q]     = *(const short*)&t0;                                                      \
                pk[q + 4] = *(const short*)&t1;                                                      \
            }                                                                                        \
            *(bf16x8*)(&(dst)[(rbase + srow) * BK + (lane & 7) * 8]) = pk;                           \
        }                                                                                            \
    } while (0)

#define COMPUTE0(buf)                                                                                \
    do {                                                                                             \
        bf16x8 af[4][2], bv[4][2];                                                                   \
        const int fr = lane & 15;                                                                    \
        const int kq = lane >> 4;                                                                    \
        _Pragma("unroll") for (int mi = 0; mi < 4; ++mi) {                                           \
            const int r = wm + mi * 16 + fr;                                                         \
            _Pragma("unroll") for (int kh = 0; kh < 2; ++kh) {                                       \
                const int c = ((kh * 4 + kq) ^ (fr & 7)) * 8;                                        \
                af[mi][kh] = *(const bf16x8*)(&AsP[buf][r * BK + c]);                                \
            }                                                                                        \
        }                                                                                            \
        _Pragma("unroll") for (int ni = 0; ni < 4; ++ni) {                                           \
            const int r = wn + ni * 16 + fr;                                                         \
            _Pragma("unroll") for (int kh = 0; kh < 2; ++kh) {                                       \
                const int c = ((kh * 4 + kq) ^ (fr & 7)) * 8;                                        \
                bv[ni][kh] = *(const bf16x8*)(&BsP[buf][r * BK + c]);                                \
            }                                                                                        \
        }                                                                                            \
        _Pragma("unroll") for (int kh = 0; kh < 2; ++kh)                                             \
            _Pragma("unroll") for (int mi = 0; mi < 4; ++mi)                                         \
                _Pragma("unroll") for (int ni = 0; ni < 4; ++ni)                                     \
                    acc[mi][ni] = __builtin_amdgcn_mfma_f32_16x16x32_bf16(af[mi][kh], bv[ni][kh],    \
                                                                          acc[mi][ni], 0, 0, 0);    \
    } while (0)

    LOAD_F32(va, Agf, 0);
    LOAD_F32(vb, Bgf, 0);
    WRITE_BF16(va, AsP[0]);
    WRITE_BF16(vb, BsP[0]);
    __syncthreads();
    int cur = 0;
#pragma unroll
    for (int kt = 1; kt < NT; ++kt) {
        LOAD_F32(va, Agf, kt * BK);
        LOAD_F32(vb, Bgf, kt * BK);
        COMPUTE0(cur);
        WRITE_BF16(va, AsP[cur ^ 1]);
        WRITE_BF16(vb, BsP[cur ^ 1]);
        __syncthreads();
        cur ^= 1;
    }
    COMPUTE0(cur);
    __syncthreads();

    {
        __hip_bfloat16* S = smem + wave * (64 * EP);
        const int cfr = lane & 15;
        const int cfq = lane >> 4;
        float bs[4];
#pragma unroll
        for (int ni = 0; ni < 4; ++ni) bs[ni] = bias[bn * BN + wn + ni * 16 + cfr];
#pragma unroll
        for (int mi = 0; mi < 4; ++mi)
#pragma unroll
            for (int ni = 0; ni < 4; ++ni)
#pragma unroll
                for (int r = 0; r < 4; ++r)
                    S[(mi * 16 + cfq * 4 + r) * EP + ni * 16 + cfr] =
                        __float2bfloat16(acc[mi][ni][r] + bs[ni]);
        const int rq = lane >> 3;
        const int cl = (lane & 7) * 8;
#pragma unroll
        for (int p = 0; p < 8; ++p) {
            const int lr = p * 8 + rq;
            bf16x8 v = *(const bf16x8*)(S + lr * EP + cl);
            *(bf16x8*)(&Cb[(size_t)(bm * BM + wm + lr) * N + bn * BN + wn + cl]) = v;
        }
    }
#undef LOAD_F32
#undef WRITE_BF16
#undef COMPUTE0
}

// ---------------- resident-B GEMM (layers 1-3) ------------------------------
// Round-13 proven skeleton (padded [64][520] B, 2-slot A, barrier-free K-loop)
// + B-fragment register pipeline: bv(t+1) ds_reads issue during MFMA(t);
// counted lgkmcnt(8) retires exactly {bv(t), af(t)} (order pinned by a
// sched_barrier between the af reads and bv issues, which also makes the
// STAGE_A slot overwrite provably safe). Accumulation order unchanged.
__global__ __launch_bounds__(512) void gemm_resB(const __hip_bfloat16* __restrict__ A,
                                                 const float* __restrict__ Btf,
                                                 const float* __restrict__ bias,
                                                 __hip_bfloat16* __restrict__ Cb) {
    constexpr int K = D;
    constexpr int N = D;
    extern __shared__ __hip_bfloat16 smem[]; // [64x520 B][8 waves x 2 x 4KB A]

    const int tid  = threadIdx.x;
    const int wave = tid >> 6;
    const int lane = tid & 63;

    const int bid = blockIdx.x;
    const int xcd = bid & 7;
    const int jb  = bid >> 3;            // 0..63
    const int bm  = xcd * 8 + (jb >> 3); // 0..63
    const int bn  = jb & 7;              // 0..7

    __hip_bfloat16* const Bsm = smem;
    __hip_bfloat16* const Awv = smem + QB_ELEMS + wave * (2 * QA_SLOT);

    const int srow = lane >> 3;
    const int sch  = lane & 7;

    const __hip_bfloat16* Agw = A + (size_t)(bm * QBM + wave * QWROWS) * K;
    const float* Bgf = Btf + (size_t)(bn * QBN) * K;

    const int fr = lane & 15;
    const int kq = lane >> 4;

    f32x4 acc[2][4] = {};

    // ---- prologue: B panel fp32 -> bf16 -> padded LDS (this wave's 8 rows),
    // A tiles 0,1 via gload_lds (issued between B loads and B writes so the
    // compiler's vmcnt wait before the ds_writes retires B but keeps A flying).
    {
        float4 vb[8][2];
#pragma unroll
        for (int jj = 0; jj < 8; ++jj) {
            const float* src = Bgf + (size_t)(wave * 8 + jj) * K + lane * 8;
            vb[jj][0] = *(const float4*)src;
            vb[jj][1] = *(const float4*)(src + 4);
        }
#define STAGE_A(slot, k0)                                                                            \
    do {                                                                                             \
        _Pragma("unroll") for (int jj = 0; jj < 4; ++jj) {                                           \
            const int rbase = jj * 8;                                                                \
            __builtin_amdgcn_global_load_lds(                                                        \
                (const __attribute__((address_space(1))) void*)(Agw + (size_t)(rbase + srow) * K + (k0) + (sch ^ srow) * 8), \
                (__attribute__((address_space(3))) void*)(Awv + (slot) * QA_SLOT + rbase * BK), 16, 0, 0); \
        }                                                                                            \
    } while (0)
        STAGE_A(0, 0);
        STAGE_A(1, BK);
#pragma unroll
        for (int jj = 0; jj < 8; ++jj) {
            const int row = wave * 8 + jj;
            bf16x8 pk;
#pragma unroll
            for (int q = 0; q < 4; ++q) {
                __hip_bfloat16 t0 = __float2bfloat16(((const float*)&vb[jj][0])[q]);
                __hip_bfloat16 t1 = __float2bfloat16(((const float*)&vb[jj][1])[q]);
                pk[q]     = *(const short*)&t0;
                pk[q + 4] = *(const short*)&t1;
            }
            *(bf16x8*)(&Bsm[row * BPAD + lane * 8]) = pk;
        }
    }
    VMCNT(4); // A0 retired; A1 in flight
    LGKM(0);  // B ds_writes visible
    SBAR();   // B published block-wide -- the only barrier

    // B-fragment register pipeline: bvr[t&1] holds tile t's B fragments.
    bf16x8 bvr[2][4][2];
#pragma unroll
    for (int ni = 0; ni < 4; ++ni)
#pragma unroll
        for (int kh = 0; kh < 2; ++kh)
            bvr[0][ni][kh] =
                *(const bf16x8*)(&Bsm[(ni * 16 + fr) * BPAD + kh * 32 + kq * 8]);

#pragma unroll
    for (int t = 0; t < NT; ++t) {
        if (t > 0) {
            if (t < NT - 1) {
                VMCNT(4); // retire tile t's A loads (keep t+1 in flight)
            } else {
                VMCNT(0); // tail
            }
        }
        const __hip_bfloat16* Asl = Awv + (t & 1) * QA_SLOT;
        bf16x8 af[2][2];
#pragma unroll
        for (int mi = 0; mi < 2; ++mi)
#pragma unroll
            for (int kh = 0; kh < 2; ++kh) {
                const int c = ((kh * 4 + kq) ^ (fr & 7)) * 8;
                af[mi][kh] = *(const bf16x8*)(&Asl[(mi * 16 + fr) * BK + c]);
            }
        __builtin_amdgcn_sched_barrier(0); // pin FIFO order: af(t) before bv(t+1)
        if (t + 1 < NT) {
#pragma unroll
            for (int ni = 0; ni < 4; ++ni)
#pragma unroll
                for (int kh = 0; kh < 2; ++kh)
                    bvr[(t + 1) & 1][ni][kh] = *(const bf16x8*)(
                        &Bsm[(ni * 16 + fr) * BPAD + (t + 1) * BK + kh * 32 + kq * 8]);
        }
        if (t + 1 < NT) {
            LGKM(8); // retire {bv(t), af(t)}; bv(t+1)'s 8 reads stay in flight
        } else {
            LGKM(0);
        }
        if (t + 2 < NT) STAGE_A(t & 1, (t + 2) * BK); // slot safe: af(t) retired
        __builtin_amdgcn_sched_barrier(0);
        __builtin_amdgcn_s_setprio(1);
#pragma unroll
        for (int kh = 0; kh < 2; ++kh)
#pragma unroll
            for (int mi = 0; mi < 2; ++mi)
#pragma unroll
                for (int ni = 0; ni < 4; ++ni)
                    acc[mi][ni] = __builtin_amdgcn_mfma_f32_16x16x32_bf16(
                        af[mi][kh], bvr[t & 1][ni][kh], acc[mi][ni], 0, 0, 0);
        __builtin_amdgcn_s_setprio(0);
    }
#undef STAGE_A

    // ---- epilogue: wave-private LDS staging, coalesced stores --------------
    {
        __hip_bfloat16* S = Awv;
        const int cfq = lane >> 4;
        float bs[4];
#pragma unroll
        for (int ni = 0; ni < 4; ++ni) bs[ni] = bias[bn * QBN + ni * 16 + fr];
#pragma unroll
        for (int mi = 0; mi < 2; ++mi)
#pragma unroll
            for (int ni = 0; ni < 4; ++ni)
#pragma unroll
                for (int r = 0; r < 4; ++r)
                    S[(mi * 16 + cfq * 4 + r) * QEP + ni * 16 + fr] =
                        __float2bfloat16(acc[mi][ni][r] + bs[ni]);
        const int rq = lane >> 3;
        const int cl = (lane & 7) * 8;
#pragma unroll
        for (int p = 0; p < 4; ++p) {
            const int lr = p * 8 + rq;
            bf16x8 v = *(const bf16x8*)(S + lr * QEP + cl);
            *(bf16x8*)(&Cb[(size_t)(bm * QBM + wave * QWROWS + lr) * N + bn * QBN + cl]) = v;
        }
    }
}

// ---------------- fused parallel scan: h_t = max(0, a_t + u*h_{t-1}) ---------
// Chunk decomposition (h>=0 domain): F_c(h) = max(m, d + e*h), e = u^CH.
template <int MODE>
__global__ __launch_bounds__(512) void scan_k(const __hip_bfloat16* __restrict__ xh,
                                              const float* __restrict__ u,
                                              float* __restrict__ outf,
                                              __hip_bfloat16* __restrict__ outb) {
    __shared__ float4 md[NCH][32];
    const int i2  = threadIdx.x & 31;
    const int c   = threadIdx.x >> 5; // 0..15
    const int idx = blockIdx.x * 64 + i2 * 2;
    const float u0 = u[idx & (D - 1)];
    const float u1 = u[(idx + 1) & (D - 1)];

    const __hip_bfloat16* p = xh + (size_t)c * CH * M_TOT + idx;
    unsigned int xv[CH];
#pragma unroll
    for (int t = 0; t < CH; ++t) xv[t] = *(const unsigned int*)(p + (size_t)t * M_TOT);

    float m0 = 0.f, d0 = 0.f, m1 = 0.f, d1 = 0.f;
#pragma unroll
    for (int t = 0; t < CH; ++t) {
        const float a0 = __uint_as_float(xv[t] << 16);
        const float a1 = __uint_as_float(xv[t] & 0xffff0000u);
        m0 = fmaxf(fmaf(u0, m0, a0), 0.f);
        d0 = fmaf(u0, d0, a0);
        m1 = fmaxf(fmaf(u1, m1, a1), 0.f);
        d1 = fmaf(u1, d1, a1);
    }
    md[c][i2] = make_float4(m0, d0, m1, d1);
    __syncthreads();

    float e0 = u0 * u0, e1 = u1 * u1;       // u^2
    e0 *= e0; e0 *= e0; e0 *= e0; e0 *= e0; // u^32 == u^CH
    e1 *= e1; e1 *= e1; e1 *= e1; e1 *= e1;
    float h0 = 0.f, h1 = 0.f;
    for (int jj = 0; jj < c; ++jj) {
        const float4 v = md[jj][i2];
        h0 = fmaxf(v.x, fmaf(e0, h0, v.y));
        h1 = fmaxf(v.z, fmaf(e1, h1, v.w));
    }

    const size_t base = (size_t)c * CH * M_TOT + idx;
#pragma unroll
    for (int t = 0; t < CH; ++t) {
        const size_t off = base + (size_t)t * M_TOT;
        const float a0 = __uint_as_float(xv[t] << 16);
        const float a1 = __uint_as_float(xv[t] & 0xffff0000u);
        h0 = fmaxf(fmaf(u0, h0, a0), 0.f);
        h1 = fmaxf(fmaf(u1, h1, a1), 0.f);
        if (MODE & 1) *(float2*)(outf + off) = make_float2(h0, h1);
        if (MODE & 2) {
            __hip_bfloat16 b0 = __float2bfloat16(h0);
            __hip_bfloat16 b1 = __float2bfloat16(h1);
            unsigned int pk = (unsigned int)(*(unsigned short*)&b0) |
                              ((unsigned int)(*(unsigned short*)&b1) << 16);
            *(unsigned int*)(outb + off) = pk;
        }
    }
}

extern "C" void kernel_launch(void* const* d_in, const int* in_sizes, int n_in,
                              void* d_out, int out_size, void* d_ws, size_t ws_size,
                              hipStream_t stream) {
    const float* x = (const float*)d_in[0]; // [T, B, Din]
    const float* W = (const float*)d_in[1]; // [L, Dh, Din]
    const float* b = (const float*)d_in[2]; // [L, Dh]
    const float* u = (const float*)d_in[3]; // [L, Dh]
    float* out = (float*)d_out;             // [T, B, Dh]

    __hip_bfloat16* Ab = (__hip_bfloat16*)d_ws;  // 16.8 MB
    __hip_bfloat16* Xh = Ab + (size_t)M_TOT * D; // 16.8 MB

    (void)hipFuncSetAttribute((const void*)gemm_resB,
                              hipFuncAttributeMaxDynamicSharedMemorySize, QSMEM_BYTES);

    for (int l = 0; l < NLAYER; ++l) {
        if (l == 0) {
            gemm_l0<<<(M_TOT / BM) * (D / BN), 256, 0, stream>>>(x, W, b, Xh);
        } else {
            gemm_resB<<<(M_TOT / QBM) * (D / QBN), 512, QSMEM_BYTES, stream>>>(
                Ab, W + (size_t)l * D * D, b + (size_t)l * D, Xh);
        }
        if (l < NLAYER - 1) {
            scan_k<2><<<M_TOT / 64, 512, 0, stream>>>(Xh, u + (size_t)l * D, nullptr, Ab);
        } else {
            scan_k<1><<<M_TOT / 64, 512, 0, stream>>>(Xh, u + (size_t)l * D, out, nullptr);
        }
    }
}

// Round 16
// 110.746 us; speedup vs baseline: 1.0221x; 1.0038x over previous
//
#include <hip/hip_runtime.h>
#include <hip/hip_bf16.h>

typedef short bf16x8 __attribute__((ext_vector_type(8)));
typedef float f32x4 __attribute__((ext_vector_type(4)));

#define T_LEN 512
#define BATCH 32
#define D 512
#define M_TOT (T_LEN * BATCH) /* 16384 */
#define NLAYER 4

/* ---- layer-0 GEMM (fp32 A and B, reg-staged converts) ---- */
#define BM 128
#define BN 128
#define BK 64
#define NT (D / BK) /* 8 K-tiles */
#define EP 72

/* ---- resident-B GEMM (layers 1-3): fp32 B panel, padded LDS ---- */
#define QBN 64                /* output cols per block */
#define QWROWS 32             /* private M-rows per wave */
#define QBM 256               /* 8 waves x 32 rows */
#define BPAD 520              /* padded B row stride (1040B -> 4-word bank rotation) */
#define QB_ELEMS (QBN * BPAD) /* 33280 elems */
#define QA_SLOT (QWROWS * BK) /* 2048 elems = 4KB per A slot */
#define QSMEM_BYTES ((QB_ELEMS + 8 * 2 * QA_SLOT) * 2) /* 132096 B */
#define QEP 72

#define CH 32            /* scan chunk length */
#define NCH (T_LEN / CH) /* 16 chunks */

#define SBAR()                             \
    do {                                   \
        __builtin_amdgcn_s_barrier();      \
        __builtin_amdgcn_sched_barrier(0); \
    } while (0)
#define VMCNT(n)                                              \
    do {                                                      \
        asm volatile("s_waitcnt vmcnt(" #n ")" ::: "memory"); \
        __builtin_amdgcn_sched_barrier(0);                    \
    } while (0)
#define LGKM0()                                               \
    do {                                                      \
        asm volatile("s_waitcnt lgkmcnt(0)" ::: "memory");    \
        __builtin_amdgcn_sched_barrier(0);                    \
    } while (0)

// ---------------- layer-0 GEMM: A = x fp32, B = W[0] fp32, both reg-staged --
// 128x128 tile, 4 waves, 2-phase dbuf, chunk-XOR swizzle (write emulates the
// gload_lds linear layout; read side unchanged), XCD swizzle, LDS epilogue.
__global__ __launch_bounds__(256) void gemm_l0(const float* __restrict__ Agf0,
                                               const float* __restrict__ Bgf0,
                                               const float* __restrict__ bias,
                                               __hip_bfloat16* __restrict__ Cb) {
    constexpr int K = D;
    constexpr int N = D;
    __shared__ __hip_bfloat16 smem[4 * BM * BK]; // 64KB
    __hip_bfloat16* const AsP[2] = {smem, smem + BM * BK};
    __hip_bfloat16* const BsP[2] = {smem + 2 * BM * BK, smem + 3 * BM * BK};

    const int tid  = threadIdx.x;
    const int wave = tid >> 6;
    const int lane = tid & 63;

    const int bid = blockIdx.x;
    const int xcd = bid & 7;
    const int jb  = bid >> 3;
    const int bm  = xcd * 16 + (jb >> 2);
    const int bn  = jb & 3;

    const int wm = (wave >> 1) * 64;
    const int wn = (wave & 1) * 64;

    const int srow = lane >> 3;
    const int scol = ((lane & 7) ^ srow) * 8;

    const float* Agf = Agf0 + (size_t)(bm * BM) * K;
    const float* Bgf = Bgf0 + (size_t)(bn * BN) * K;

    f32x4 acc[4][4] = {};
    float4 va[4][2], vb[4][2];

#define LOAD_F32(vr, base, k0)                                                                       \
    do {                                                                                             \
        _Pragma("unroll") for (int jj = 0; jj < 4; ++jj) {                                           \
            const int rbase = (jj * 4 + wave) * 8;                                                   \
            const float* sp = (base) + (size_t)(rbase + srow) * K + (k0) + scol;                     \
            vr[jj][0] = *(const float4*)sp;                                                          \
            vr[jj][1] = *(const float4*)(sp + 4);                                                    \
        }                                                                                            \
    } while (0)

#define WRITE_BF16(vr, dst)                                                                          \
    do {                                                                                             \
        _Pragma("unroll") for (int jj = 0; jj < 4; ++jj) {                                           \
            const int rbase = (jj * 4 + wave) * 8;                                                   \
            bf16x8 pk;                                                                               \
            _Pragma("unroll") for (int q = 0; q < 4; ++q) {                                          \
                __hip_bfloat16 t0 = __float2bfloat16(((const float*)&vr[jj][0])[q]);                 \
                __hip_bfloat16 t1 = __float2bfloat16(((const float*)&vr[jj][1])[q]);                 \
                pk[q]     = *(const short*)&t0;                                                      \
                pk[q + 4] = *(const short*)&t1;                                                      \
            }                                                                                        \
            *(bf16x8*)(&(dst)[(rbase + srow) * BK + (lane & 7) * 8]) = pk;                           \
        }                                                                                            \
    } while (0)

#define COMPUTE0(buf)                                                                                \
    do {                                                                                             \
        bf16x8 af[4][2], bv[4][2];                                                                   \
        const int fr = lane & 15;                                                                    \
        const int kq = lane >> 4;                                                                    \
        _Pragma("unroll") for (int mi = 0; mi < 4; ++mi) {                                           \
            const int r = wm + mi * 16 + fr;                                                         \
            _Pragma("unroll") for (int kh = 0; kh < 2; ++kh) {                                       \
                const int c = ((kh * 4 + kq) ^ (fr & 7)) * 8;                                        \
                af[mi][kh] = *(const bf16x8*)(&AsP[buf][r * BK + c]);                                \
            }                                                                                        \
        }                                                                                            \
        _Pragma("unroll") for (int ni = 0; ni < 4; ++ni) {                                           \
            const int r = wn + ni * 16 + fr;                                                         \
            _Pragma("unroll") for (int kh = 0; kh < 2; ++kh) {                                       \
                const int c = ((kh * 4 + kq) ^ (fr & 7)) * 8;                                        \
                bv[ni][kh] = *(const bf16x8*)(&BsP[buf][r * BK + c]);                                \
            }                                                                                        \
        }                                                                                            \
        _Pragma("unroll") for (int kh = 0; kh < 2; ++kh)                                             \
            _Pragma("unroll") for (int mi = 0; mi < 4; ++mi)                                         \
                _Pragma("unroll") for (int ni = 0; ni < 4; ++ni)                                     \
                    acc[mi][ni] = __builtin_amdgcn_mfma_f32_16x16x32_bf16(af[mi][kh], bv[ni][kh],    \
                                                                          acc[mi][ni], 0, 0, 0);    \
    } while (0)

    LOAD_F32(va, Agf, 0);
    LOAD_F32(vb, Bgf, 0);
    WRITE_BF16(va, AsP[0]);
    WRITE_BF16(vb, BsP[0]);
    __syncthreads();
    int cur = 0;
#pragma unroll
    for (int kt = 1; kt < NT; ++kt) {
        LOAD_F32(va, Agf, kt * BK);   // issue early (T14)
        LOAD_F32(vb, Bgf, kt * BK);
        COMPUTE0(cur);                // hide global latency under MFMA
        WRITE_BF16(va, AsP[cur ^ 1]); // vmcnt lands here, after compute
        WRITE_BF16(vb, BsP[cur ^ 1]);
        __syncthreads();
        cur ^= 1;
    }
    COMPUTE0(cur);
    __syncthreads();

    {
        __hip_bfloat16* S = smem + wave * (64 * EP);
        const int cfr = lane & 15;
        const int cfq = lane >> 4;
        float bs[4];
#pragma unroll
        for (int ni = 0; ni < 4; ++ni) bs[ni] = bias[bn * BN + wn + ni * 16 + cfr];
#pragma unroll
        for (int mi = 0; mi < 4; ++mi)
#pragma unroll
            for (int ni = 0; ni < 4; ++ni)
#pragma unroll
                for (int r = 0; r < 4; ++r)
                    S[(mi * 16 + cfq * 4 + r) * EP + ni * 16 + cfr] =
                        __float2bfloat16(acc[mi][ni][r] + bs[ni]);
        const int rq = lane >> 3;
        const int cl = (lane & 7) * 8;
#pragma unroll
        for (int p = 0; p < 8; ++p) {
            const int lr = p * 8 + rq;
            bf16x8 v = *(const bf16x8*)(S + lr * EP + cl);
            *(bf16x8*)(&Cb[(size_t)(bm * BM + wm + lr) * N + bn * BN + wn + cl]) = v;
        }
    }
#undef LOAD_F32
#undef WRITE_BF16
#undef COMPUTE0
}

// ---------------- resident-B GEMM (layers 1-3) ------------------------------
// Round-13 proven configuration: B panel sourced from fp32 W (in-reg convert)
// into PADDED LDS [64][520] (bank-rotated, conflict-free b128 reads), 2-slot
// wave-private A via gload_lds, barrier-free K-loop with wave-local counted
// vmcnt. Best measured: 110.8 us total.
__global__ __launch_bounds__(512) void gemm_resB(const __hip_bfloat16* __restrict__ A,
                                                 const float* __restrict__ Btf,
                                                 const float* __restrict__ bias,
                                                 __hip_bfloat16* __restrict__ Cb) {
    constexpr int K = D;
    constexpr int N = D;
    extern __shared__ __hip_bfloat16 smem[]; // [64x520 B][8 waves x 2 x 4KB A]

    const int tid  = threadIdx.x;
    const int wave = tid >> 6;
    const int lane = tid & 63;

    const int bid = blockIdx.x;
    const int xcd = bid & 7;
    const int jb  = bid >> 3;            // 0..63
    const int bm  = xcd * 8 + (jb >> 3); // 0..63
    const int bn  = jb & 7;              // 0..7

    __hip_bfloat16* const Bsm = smem;
    __hip_bfloat16* const Awv = smem + QB_ELEMS + wave * (2 * QA_SLOT);

    const int srow = lane >> 3;
    const int sch  = lane & 7;

    const __hip_bfloat16* Agw = A + (size_t)(bm * QBM + wave * QWROWS) * K;
    const float* Bgf = Btf + (size_t)(bn * QBN) * K;

    const int fr = lane & 15;
    const int kq = lane >> 4;

    f32x4 acc[2][4] = {};

    // ---- prologue: B panel fp32 -> bf16 -> padded LDS (this wave's 8 rows),
    // then A tiles 0,1 via gload_lds. Load order keeps A youngest in vmcnt.
    {
        float4 vb[8][2];
#pragma unroll
        for (int jj = 0; jj < 8; ++jj) {
            const float* src = Bgf + (size_t)(wave * 8 + jj) * K + lane * 8;
            vb[jj][0] = *(const float4*)src;
            vb[jj][1] = *(const float4*)(src + 4);
        }
#define STAGE_A(slot, k0)                                                                            \
    do {                                                                                             \
        _Pragma("unroll") for (int jj = 0; jj < 4; ++jj) {                                           \
            const int rbase = jj * 8;                                                                \
            __builtin_amdgcn_global_load_lds(                                                        \
                (const __attribute__((address_space(1))) void*)(Agw + (size_t)(rbase + srow) * K + (k0) + (sch ^ srow) * 8), \
                (__attribute__((address_space(3))) void*)(Awv + (slot) * QA_SLOT + rbase * BK), 16, 0, 0); \
        }                                                                                            \
    } while (0)
        STAGE_A(0, 0);
        STAGE_A(1, BK);
#pragma unroll
        for (int jj = 0; jj < 8; ++jj) { // compiler waits vmcnt(8): A stays in flight
            const int row = wave * 8 + jj;
            bf16x8 pk;
#pragma unroll
            for (int q = 0; q < 4; ++q) {
                __hip_bfloat16 t0 = __float2bfloat16(((const float*)&vb[jj][0])[q]);
                __hip_bfloat16 t1 = __float2bfloat16(((const float*)&vb[jj][1])[q]);
                pk[q]     = *(const short*)&t0;
                pk[q + 4] = *(const short*)&t1;
            }
            *(bf16x8*)(&Bsm[row * BPAD + lane * 8]) = pk;
        }
    }
    VMCNT(4); // A0 retired; A1 in flight
    LGKM0();  // B ds_writes visible
    SBAR();   // B published block-wide -- the only barrier

#pragma unroll
    for (int t = 0; t < NT; ++t) {
        if (t > 0) {
            if (t < NT - 1) {
                VMCNT(4); // retire tile t (keep t+1 in flight)
            } else {
                VMCNT(0); // tail
            }
        }
        const __hip_bfloat16* Asl = Awv + (t & 1) * QA_SLOT;
        bf16x8 af[2][2], bv[4][2];
#pragma unroll
        for (int mi = 0; mi < 2; ++mi)
#pragma unroll
            for (int kh = 0; kh < 2; ++kh) {
                const int c = ((kh * 4 + kq) ^ (fr & 7)) * 8;
                af[mi][kh] = *(const bf16x8*)(&Asl[(mi * 16 + fr) * BK + c]);
            }
#pragma unroll
        for (int ni = 0; ni < 4; ++ni)
#pragma unroll
            for (int kh = 0; kh < 2; ++kh) {
                // padded layout: plain addressing, bank-rotated by BPAD
                bv[ni][kh] = *(const bf16x8*)(&Bsm[(ni * 16 + fr) * BPAD + t * BK + kh * 32 + kq * 8]);
            }
        LGKM0(); // reads landed: slot (t&1) free, MFMA ordering pinned
        if (t + 2 < NT) STAGE_A(t & 1, (t + 2) * BK); // wave-private, no barrier
        __builtin_amdgcn_sched_barrier(0);
        __builtin_amdgcn_s_setprio(1);
#pragma unroll
        for (int kh = 0; kh < 2; ++kh)
#pragma unroll
            for (int mi = 0; mi < 2; ++mi)
#pragma unroll
                for (int ni = 0; ni < 4; ++ni)
                    acc[mi][ni] = __builtin_amdgcn_mfma_f32_16x16x32_bf16(af[mi][kh], bv[ni][kh],
                                                                          acc[mi][ni], 0, 0, 0);
        __builtin_amdgcn_s_setprio(0);
    }
#undef STAGE_A

    // ---- epilogue: wave-private LDS staging, coalesced stores --------------
    {
        __hip_bfloat16* S = Awv;
        const int cfq = lane >> 4;
        float bs[4];
#pragma unroll
        for (int ni = 0; ni < 4; ++ni) bs[ni] = bias[bn * QBN + ni * 16 + fr];
#pragma unroll
        for (int mi = 0; mi < 2; ++mi)
#pragma unroll
            for (int ni = 0; ni < 4; ++ni)
#pragma unroll
                for (int r = 0; r < 4; ++r)
                    S[(mi * 16 + cfq * 4 + r) * QEP + ni * 16 + fr] =
                        __float2bfloat16(acc[mi][ni][r] + bs[ni]);
        const int rq = lane >> 3;
        const int cl = (lane & 7) * 8;
#pragma unroll
        for (int p = 0; p < 4; ++p) {
            const int lr = p * 8 + rq;
            bf16x8 v = *(const bf16x8*)(S + lr * QEP + cl);
            *(bf16x8*)(&Cb[(size_t)(bm * QBM + wave * QWROWS + lr) * N + bn * QBN + cl]) = v;
        }
    }
}

// ---------------- fused parallel scan: h_t = max(0, a_t + u*h_{t-1}) ---------
// Chunk decomposition (h>=0 domain): F_c(h) = max(m, d + e*h), e = u^CH.
template <int MODE>
__global__ __launch_bounds__(512) void scan_k(const __hip_bfloat16* __restrict__ xh,
                                              const float* __restrict__ u,
                                              float* __restrict__ outf,
                                              __hip_bfloat16* __restrict__ outb) {
    __shared__ float4 md[NCH][32];
    const int i2  = threadIdx.x & 31;
    const int c   = threadIdx.x >> 5; // 0..15
    const int idx = blockIdx.x * 64 + i2 * 2;
    const float u0 = u[idx & (D - 1)];
    const float u1 = u[(idx + 1) & (D - 1)];

    const __hip_bfloat16* p = xh + (size_t)c * CH * M_TOT + idx;
    unsigned int xv[CH];
#pragma unroll
    for (int t = 0; t < CH; ++t) xv[t] = *(const unsigned int*)(p + (size_t)t * M_TOT);

    float m0 = 0.f, d0 = 0.f, m1 = 0.f, d1 = 0.f;
#pragma unroll
    for (int t = 0; t < CH; ++t) {
        const float a0 = __uint_as_float(xv[t] << 16);
        const float a1 = __uint_as_float(xv[t] & 0xffff0000u);
        m0 = fmaxf(fmaf(u0, m0, a0), 0.f);
        d0 = fmaf(u0, d0, a0);
        m1 = fmaxf(fmaf(u1, m1, a1), 0.f);
        d1 = fmaf(u1, d1, a1);
    }
    md[c][i2] = make_float4(m0, d0, m1, d1);
    __syncthreads();

    float e0 = u0 * u0, e1 = u1 * u1;       // u^2
    e0 *= e0; e0 *= e0; e0 *= e0; e0 *= e0; // u^32 == u^CH
    e1 *= e1; e1 *= e1; e1 *= e1; e1 *= e1;
    float h0 = 0.f, h1 = 0.f;
    for (int jj = 0; jj < c; ++jj) {
        const float4 v = md[jj][i2];
        h0 = fmaxf(v.x, fmaf(e0, h0, v.y));
        h1 = fmaxf(v.z, fmaf(e1, h1, v.w));
    }

    const size_t base = (size_t)c * CH * M_TOT + idx;
#pragma unroll
    for (int t = 0; t < CH; ++t) {
        const size_t off = base + (size_t)t * M_TOT;
        const float a0 = __uint_as_float(xv[t] << 16);
        const float a1 = __uint_as_float(xv[t] & 0xffff0000u);
        h0 = fmaxf(fmaf(u0, h0, a0), 0.f);
        h1 = fmaxf(fmaf(u1, h1, a1), 0.f);
        if (MODE & 1) *(float2*)(outf + off) = make_float2(h0, h1);
        if (MODE & 2) {
            __hip_bfloat16 b0 = __float2bfloat16(h0);
            __hip_bfloat16 b1 = __float2bfloat16(h1);
            unsigned int pk = (unsigned int)(*(unsigned short*)&b0) |
                              ((unsigned int)(*(unsigned short*)&b1) << 16);
            *(unsigned int*)(outb + off) = pk;
        }
    }
}

extern "C" void kernel_launch(void* const* d_in, const int* in_sizes, int n_in,
                              void* d_out, int out_size, void* d_ws, size_t ws_size,
                              hipStream_t stream) {
    const float* x = (const float*)d_in[0]; // [T, B, Din]
    const float* W = (const float*)d_in[1]; // [L, Dh, Din]
    const float* b = (const float*)d_in[2]; // [L, Dh]
    const float* u = (const float*)d_in[3]; // [L, Dh]
    float* out = (float*)d_out;             // [T, B, Dh]

    __hip_bfloat16* Ab = (__hip_bfloat16*)d_ws;  // 16.8 MB
    __hip_bfloat16* Xh = Ab + (size_t)M_TOT * D; // 16.8 MB

    (void)hipFuncSetAttribute((const void*)gemm_resB,
                              hipFuncAttributeMaxDynamicSharedMemorySize, QSMEM_BYTES);

    for (int l = 0; l < NLAYER; ++l) {
        if (l == 0) {
            gemm_l0<<<(M_TOT / BM) * (D / BN), 256, 0, stream>>>(x, W, b, Xh);
        } else {
            gemm_resB<<<(M_TOT / QBM) * (D / QBN), 512, QSMEM_BYTES, stream>>>(
                Ab, W + (size_t)l * D * D, b + (size_t)l * D, Xh);
        }
        if (l < NLAYER - 1) {
            scan_k<2><<<M_TOT / 64, 512, 0, stream>>>(Xh, u + (size_t)l * D, nullptr, Ab);
        } else {
            scan_k<1><<<M_TOT / 64, 512, 0, stream>>>(Xh, u + (size_t)l * D, out, nullptr);
        }
    }
}